// Round 8
// baseline (319.486 us; speedup 1.0000x reference)
//
#include <hip/hip_runtime.h>
#include <math.h>

#define NN 50000
#define EE 800000
#define HIDF 128
#define NPAD 50176   // padded rows for tile overrun (391*128 = 50048)

#define BSHIFT 9
#define BKTN 98      // ceil(50000 / 512)
#define BCAP 10000   // max edges per bucket (mean 8163 -> huge margin)

typedef unsigned int uint;
typedef unsigned short ushort;
typedef unsigned char uchar;
typedef short bf16x8 __attribute__((ext_vector_type(8)));
typedef float f32x4 __attribute__((ext_vector_type(4)));

__device__ inline ushort bf16_rtne(float x) {
  uint u = __float_as_uint(x);
  return (ushort)((u + 0x7fffu + ((u >> 16) & 1u)) >> 16);
}
__device__ inline uint pack2_bf16(float a, float b) {
  return (uint)bf16_rtne(a) | ((uint)bf16_rtne(b) << 16);
}
__device__ inline float lo16(uint z) { return __uint_as_float(z << 16); }
__device__ inline float hi16(uint z) { return __uint_as_float(z & 0xffff0000u); }

// ===================== Prep: W2 frags + wel/wer + zeroing + layer-1 node transform =====
__global__ void k_prep(const float* __restrict__ x, const float* __restrict__ W1,
                       const float* __restrict__ al1, const float* __restrict__ ar1,
                       const float* __restrict__ W2, const float* __restrict__ al2,
                       const float* __restrict__ ar2,
                       ushort* __restrict__ z, float* __restrict__ el, float* __restrict__ er,
                       ushort* __restrict__ Bfrag, float* __restrict__ wel,
                       float* __restrict__ wer, int* __restrict__ bcnt,
                       float* __restrict__ el2, float* __restrict__ er2,
                       float* __restrict__ out3) {
  int b = blockIdx.x, tid = threadIdx.x;
  if (b < 16) {
    int e = b * 1024 + tid * 4;
#pragma unroll
    for (int q = 0; q < 4; ++q, ++e) {
      int k = e >> 7, n = e & 127;
      float v = W2[e];
      ushort hi = bf16_rtne(v);
      ushort lo = bf16_rtne(v - __uint_as_float((uint)hi << 16));
      int g = n >> 4, t = k >> 5;
      int l = (n & 15) | (((k >> 3) & 3) << 4);
      int j = k & 7;
      int idx = ((g * 4 + t) * 64 + l) * 8 + j;
      Bfrag[idx] = hi;
      Bfrag[16384 + idx] = lo;
    }
  } else if (b == 16) {
    if (tid < BKTN) bcnt[tid] = 0;
    if (tid < 128) {
      float acc = 0.f;
      for (int k = 0; k < 128; ++k) acc += W2[k * 128 + tid] * al2[k];
      wel[tid] = acc;
    } else {
      int n = tid - 128;
      float acc = 0.f;
      for (int k = 0; k < 128; ++k) acc += W2[k * 128 + n] * ar2[k];
      wer[n] = acc;
    }
  } else {
    int v = (b - 17) * 4 + (tid >> 6);
    if (v >= NN) return;
    int lane = tid & 63;
    float x0 = x[v * 2 + 0];
    float x1 = x[v * 2 + 1];
    int f0 = lane * 2, f1 = f0 + 1;
    float z0 = fmaf(x0, W1[f0], x1 * W1[HIDF + f0]);
    float z1v = fmaf(x0, W1[f1], x1 * W1[HIDF + f1]);
    ((uint*)(z + (size_t)v * HIDF))[lane] = pack2_bf16(z0, z1v);
    float elp = z0 * al1[f0] + z1v * al1[f1];
    float erp = z0 * ar1[f0] + z1v * ar1[f1];
    for (int o = 32; o; o >>= 1) {
      elp += __shfl_xor(elp, o);
      erp += __shfl_xor(erp, o);
    }
    if (lane == 0) {
      el[v] = elp; er[v] = erp;
      el2[v] = 0.f; er2[v] = 0.f;
      out3[v] = 0.f; out3[NN + v] = 0.f; out3[2 * NN + v] = 0.f;
    }
  }
}

// ===================== CSR build: LDS-staged two-level binning =====================
__global__ __launch_bounds__(256) void k_binA(const int* __restrict__ src,
                                              const int* __restrict__ dst,
                                              int* __restrict__ bcnt, uint* __restrict__ bcoo) {
  __shared__ uint stage[4096];
  __shared__ uchar stageb[4096];
  __shared__ int bh[BKTN], bbase[BKTN], gbase[BKTN], lcur[BKTN];
  __shared__ int sc[128];
  int tid = threadIdx.x;
  int e0 = blockIdx.x * 4096;
  int nE = min(4096, EE - e0);
  if (tid < BKTN) bh[tid] = 0;
  __syncthreads();

  int myb[16];
  uint myv[16];
#pragma unroll
  for (int k = 0; k < 16; ++k) {
    int i = e0 + k * 256 + tid;
    myb[k] = -1;
    if (i < EE) {
      int s = src[i], d = dst[i];
      myb[k] = d >> BSHIFT;
      myv[k] = ((uint)s << BSHIFT) | (uint)(d & 511);
      atomicAdd(&bh[myb[k]], 1);
    }
  }
  __syncthreads();

  {
    int v = (tid < BKTN) ? bh[tid] : 0;
    if (tid < 128) sc[tid] = v;
    __syncthreads();
    for (int o = 1; o < 128; o <<= 1) {
      int add = (tid >= o && tid < 128) ? sc[tid - o] : 0;
      __syncthreads();
      if (tid < 128) sc[tid] += add;
      __syncthreads();
    }
    if (tid < BKTN) {
      int excl = sc[tid] - bh[tid];
      bbase[tid] = excl;
      lcur[tid] = excl;
      gbase[tid] = atomicAdd(&bcnt[tid], bh[tid]);
    }
  }
  __syncthreads();

#pragma unroll
  for (int k = 0; k < 16; ++k) {
    if (myb[k] >= 0) {
      int slot = atomicAdd(&lcur[myb[k]], 1);
      stage[slot] = myv[k];
      stageb[slot] = (uchar)myb[k];
    }
  }
  __syncthreads();

  for (int s2 = tid; s2 < nE; s2 += 256) {
    int b = stageb[s2];
    bcoo[(size_t)b * BCAP + gbase[b] + (s2 - bbase[b])] = stage[s2];
  }
}

// Pass B: per-bucket counting sort; also emits per-edge dst (dstc) for the p-kernels.
__global__ __launch_bounds__(256) void k_binB(const uint* __restrict__ bcoo,
                                              const int* __restrict__ bcnt,
                                              int* __restrict__ rowp, int* __restrict__ srcs,
                                              int* __restrict__ dstc) {
  __shared__ int h[512], pref[512], ps[256];
  __shared__ int basebuf;
  int b = blockIdx.x, tid = threadIdx.x;
  int cnt = bcnt[b];

  {
    int v = (tid < BKTN) ? bcnt[tid] : 0;
    if (tid < 128) ps[tid] = v;
    __syncthreads();
    for (int o = 1; o < 128; o <<= 1) {
      int add = (tid >= o && tid < 128) ? ps[tid - o] : 0;
      __syncthreads();
      if (tid < 128) ps[tid] += add;
      __syncthreads();
    }
    if (tid == 0) {
      basebuf = (b == 0) ? 0 : ps[b - 1];
      if (b == 0) rowp[NN] = EE;
    }
  }
  h[tid] = 0;
  h[tid + 256] = 0;
  __syncthreads();
  int base = basebuf;
  const uint* mc = bcoo + (size_t)b * BCAP;
  for (int i = tid; i < cnt; i += 256) atomicAdd(&h[mc[i] & 511], 1);
  __syncthreads();
  int a0 = h[2 * tid], a1 = h[2 * tid + 1];
  int s = a0 + a1;
  ps[tid] = s;
  __syncthreads();
  for (int o = 1; o < 256; o <<= 1) {
    int add = (tid >= o) ? ps[tid - o] : 0;
    __syncthreads();
    ps[tid] += add;
    __syncthreads();
  }
  int excl = ps[tid] - s;
  pref[2 * tid] = excl;
  pref[2 * tid + 1] = excl + a0;
  __syncthreads();
  int n0 = b << BSHIFT;
  for (int j = tid; j < 512; j += 256)
    if (n0 + j < NN) rowp[n0 + j] = base + pref[j];
  __syncthreads();
  for (int i = tid; i < cnt; i += 256) {
    uint v = mc[i];
    int pos = atomicAdd(&pref[v & 511], 1);
    srcs[base + pos] = (int)(v >> BSHIFT);
    dstc[base + pos] = n0 + (int)(v & 511);
  }
}

// ===================== Per-edge attention weight: e2[j] = {src, exp(leaky(el+er))} =====
__global__ void k_edgep(const int* __restrict__ srcs, const int* __restrict__ dstc,
                        const float* __restrict__ el, const float* __restrict__ er,
                        uint2* __restrict__ e2) {
  int j = blockIdx.x * 256 + threadIdx.x;
  if (j >= EE) return;
  int s = srcs[j];
  float t = el[s] + er[dstc[j]];
  t = fmaxf(t, 0.2f * t);
  e2[j] = make_uint2((uint)s, __float_as_uint(__expf(t)));
}

// ===================== Layer 2 GEMM via MFMA bf16x2-split =====================
__global__ __launch_bounds__(256) void k_gemm_mfma(
    const ushort* __restrict__ Hhi, const ushort* __restrict__ Hlo,
    const ushort* __restrict__ Bfrag, ushort* __restrict__ z) {
  int tid = threadIdx.x;
  int lane = tid & 63;
  int wid = tid >> 6;
  int base = blockIdx.x * 128;

  bf16x8 bhi[2][4], blo[2][4];
  const bf16x8* bp = (const bf16x8*)Bfrag;
#pragma unroll
  for (int gi = 0; gi < 2; ++gi)
#pragma unroll
    for (int t = 0; t < 4; ++t) {
      int idx = ((wid * 2 + gi) * 4 + t) * 64 + lane;
      bhi[gi][t] = bp[idx];
      blo[gi][t] = bp[2048 + idx];
    }

  int arow = lane & 15;
  int koff = (lane >> 4) * 8;
  const bf16x8* ahp = (const bf16x8*)(Hhi + (size_t)(base + arow) * HIDF + koff);
  const bf16x8* alp = (const bf16x8*)(Hlo + (size_t)(base + arow) * HIDF + koff);

  bf16x8 ah[4], av[4];
#pragma unroll
  for (int t = 0; t < 4; ++t) { ah[t] = ahp[t * 4]; av[t] = alp[t * 4]; }

#pragma unroll
  for (int mt = 0; mt < 8; ++mt) {
    bf16x8 nah[4], nav[4];
#pragma unroll
    for (int t = 0; t < 4; ++t) { nah[t] = ah[t]; nav[t] = av[t]; }
    if (mt < 7) {
#pragma unroll
      for (int t = 0; t < 4; ++t) {
        nah[t] = ahp[(mt + 1) * 256 + t * 4];
        nav[t] = alp[(mt + 1) * 256 + t * 4];
      }
    }
    f32x4 c0a = {0.f, 0.f, 0.f, 0.f}, c0b = {0.f, 0.f, 0.f, 0.f};
    f32x4 c1a = {0.f, 0.f, 0.f, 0.f}, c1b = {0.f, 0.f, 0.f, 0.f};
#pragma unroll
    for (int t = 0; t < 4; ++t) {
      f32x4& c0 = (t & 1) ? c0b : c0a;
      f32x4& c1 = (t & 1) ? c1b : c1a;
      c0 = __builtin_amdgcn_mfma_f32_16x16x32_bf16(ah[t], bhi[0][t], c0, 0, 0, 0);
      c1 = __builtin_amdgcn_mfma_f32_16x16x32_bf16(ah[t], bhi[1][t], c1, 0, 0, 0);
      c0 = __builtin_amdgcn_mfma_f32_16x16x32_bf16(ah[t], blo[0][t], c0, 0, 0, 0);
      c1 = __builtin_amdgcn_mfma_f32_16x16x32_bf16(ah[t], blo[1][t], c1, 0, 0, 0);
      c0 = __builtin_amdgcn_mfma_f32_16x16x32_bf16(av[t], bhi[0][t], c0, 0, 0, 0);
      c1 = __builtin_amdgcn_mfma_f32_16x16x32_bf16(av[t], bhi[1][t], c1, 0, 0, 0);
    }
    f32x4 c0 = c0a + c0b;
    f32x4 c1 = c1a + c1b;
    int r0 = base + mt * 16 + (lane >> 4) * 4;
    int cc = wid * 32 + (lane & 15);
    ushort* zp = z + (size_t)r0 * HIDF + cc;
#pragma unroll
    for (int i = 0; i < 4; ++i) {
      zp[i * HIDF] = bf16_rtne(c0[i]);
      zp[i * HIDF + 16] = bf16_rtne(c1[i]);
    }
#pragma unroll
    for (int t = 0; t < 4; ++t) { ah[t] = nah[t]; av[t] = nav[t]; }
  }
}

// ===================== Feature-quartered edge aggregate =====================
// blockIdx&3 = feature quarter q (32 feats); with bid%8 -> XCD, each XCD touches only
// one 3.2MB Z-quarter (L2-resident). Wave = one node; 4 16-lane groups each handle one
// edge: group loads the 64B quarter-slice of z[src] (1 L2 line), p broadcast via the
// precomputed uint2{src,p} stream. No readlanes.
// MODE 1: h quarter -> Hhi/Hlo slices + atomic el2/er2 partials (wel=W2@al2 etc.)
// MODE 2: final-head partials -> atomic out3[c*NN+v]  (wel = Wlin)
template <int MODE>
__global__ __launch_bounds__(256) void k_aggq(
    const int* __restrict__ rowp, const uint2* __restrict__ e2,
    const ushort* __restrict__ z, const float* __restrict__ bias,
    ushort* __restrict__ Hhi, ushort* __restrict__ Hlo,
    const float* __restrict__ wel, const float* __restrict__ wer,
    float* __restrict__ el2, float* __restrict__ er2,
    float* __restrict__ out3) {
  int bid = blockIdx.x;
  int q = bid & 3;
  int v = (bid >> 2) * 4 + (threadIdx.x >> 6);
  if (v >= NN) return;
  int lane = threadIdx.x & 63;
  int g = lane >> 4, li = lane & 15;
  int beg = rowp[v], end = rowp[v + 1];
  const uint* zw = (const uint*)z;
  uint qoff = (uint)(q * 16 + li);

  // denominator (all quarters recompute; cheap)
  float ps = 0.f;
  for (int cb = beg; cb < end; cb += 64) {
    int j = cb + lane;
    if (j < end) ps += __uint_as_float(e2[j].y);
  }
  for (int o = 32; o; o >>= 1) ps += __shfl_xor(ps, o);

  float a0 = 0.f, a1 = 0.f;
  int jj = beg;
  for (; jj + 8 <= end; jj += 8) {
    uint2 eA = e2[jj + g];
    uint2 eB = e2[jj + 4 + g];
    uint zA = zw[eA.x * 64u + qoff];
    uint zB = zw[eB.x * 64u + qoff];
    float pA = __uint_as_float(eA.y), pB = __uint_as_float(eB.y);
    a0 = fmaf(pA, lo16(zA), a0);
    a1 = fmaf(pA, hi16(zA), a1);
    a0 = fmaf(pB, lo16(zB), a0);
    a1 = fmaf(pB, hi16(zB), a1);
  }
  for (; jj < end; jj += 4) {
    int j = jj + g;
    bool valid = j < end;
    uint2 eA = e2[valid ? j : beg];
    float pA = valid ? __uint_as_float(eA.y) : 0.f;
    uint zA = zw[eA.x * 64u + qoff];
    a0 = fmaf(pA, lo16(zA), a0);
    a1 = fmaf(pA, hi16(zA), a1);
  }
  // combine the 4 edge-groups
  a0 += __shfl_xor(a0, 16);
  a0 += __shfl_xor(a0, 32);
  a1 += __shfl_xor(a1, 16);
  a1 += __shfl_xor(a1, 32);

  float inv = 1.0f / (ps + 1e-9f);
  int f0 = q * 32 + li * 2;
  float ox = fmaxf(fmaf(a0, inv, bias[f0]), 0.f);
  float oy = fmaxf(fmaf(a1, inv, bias[f0 + 1]), 0.f);

  if (lane >= 16) return;

  if (MODE == 1) {
    ushort hx = bf16_rtne(ox), hy = bf16_rtne(oy);
    ((uint*)Hhi)[(size_t)v * 64 + qoff] = (uint)hx | ((uint)hy << 16);
    float lx = ox - __uint_as_float((uint)hx << 16);
    float ly = oy - __uint_as_float((uint)hy << 16);
    ((uint*)Hlo)[(size_t)v * 64 + qoff] = pack2_bf16(lx, ly);
    float ep = ox * wel[f0] + oy * wel[f0 + 1];
    float rp = ox * wer[f0] + oy * wer[f0 + 1];
    for (int o = 8; o; o >>= 1) {
      ep += __shfl_xor(ep, o);
      rp += __shfl_xor(rp, o);
    }
    if (li == 0) {
      atomicAdd(&el2[v], ep);
      atomicAdd(&er2[v], rp);
    }
  } else {
    const float* wr = wel + f0 * 3;   // wel = Wlin [128,3]
    float d0 = ox * wr[0] + oy * wr[3];
    float d1 = ox * wr[1] + oy * wr[4];
    float d2 = ox * wr[2] + oy * wr[5];
    for (int o = 8; o; o >>= 1) {
      d0 += __shfl_xor(d0, o);
      d1 += __shfl_xor(d1, o);
      d2 += __shfl_xor(d2, o);
    }
    if (li == 0) {
      atomicAdd(&out3[v], d0);
      atomicAdd(&out3[NN + v], d1);
      atomicAdd(&out3[2 * NN + v], d2);
    }
  }
}

// ===================== Final head: sigmoid + mean =====================
__global__ void k_final(const float* __restrict__ out3, const float* __restrict__ blin,
                        float* __restrict__ out) {
  int v = blockIdx.x * 256 + threadIdx.x;
  if (v >= NN) return;
  float s0 = 1.f / (1.f + __expf(-(out3[v] + blin[0])));
  float s1 = 1.f / (1.f + __expf(-(out3[NN + v] + blin[1])));
  float s2 = 1.f / (1.f + __expf(-(out3[2 * NN + v] + blin[2])));
  out[v] = (s0 + s1 + s2) * (1.f / 3.f);
}

// ===================== host =====================
extern "C" void kernel_launch(void* const* d_in, const int* in_sizes, int n_in,
                              void* d_out, int out_size, void* d_ws, size_t ws_size,
                              hipStream_t stream) {
  const float* x    = (const float*)d_in[0];
  const int*   src  = (const int*)d_in[1];
  const int*   dst  = (const int*)d_in[2];
  const float* W1   = (const float*)d_in[3];
  const float* al1  = (const float*)d_in[4];
  const float* ar1  = (const float*)d_in[5];
  const float* b1   = (const float*)d_in[6];
  const float* W2   = (const float*)d_in[7];
  const float* al2  = (const float*)d_in[8];
  const float* ar2  = (const float*)d_in[9];
  const float* b2   = (const float*)d_in[10];
  const float* Wlin = (const float*)d_in[11];
  const float* blin = (const float*)d_in[12];
  float* out = (float*)d_out;

  char* ws = (char*)d_ws;
  size_t off = 0;
  auto alloc = [&](size_t bytes) -> char* {
    char* p = ws + off;
    off += (bytes + 255) & ~(size_t)255;
    return p;
  };
  int*    rowp  = (int*)alloc((size_t)(NN + 1) * 4);
  int*    srcs  = (int*)alloc((size_t)EE * 4);
  int*    dstc  = (int*)alloc((size_t)EE * 4);
  uint2*  e2    = (uint2*)alloc((size_t)EE * 8);
  int*    bcnt  = (int*)alloc(BKTN * 4);
  uint*   bcoo  = (uint*)alloc((size_t)BKTN * BCAP * 4);
  float*  el1   = (float*)alloc((size_t)NN * 4);
  float*  er1   = (float*)alloc((size_t)NN * 4);
  float*  el2   = (float*)alloc((size_t)NN * 4);
  float*  er2   = (float*)alloc((size_t)NN * 4);
  float*  out3  = (float*)alloc((size_t)NN * 3 * 4);
  float*  wel   = (float*)alloc(HIDF * 4);
  float*  wer   = (float*)alloc(HIDF * 4);
  ushort* Bfrag = (ushort*)alloc(2 * 16384 * 2);            // hi+lo frag planes
  ushort* Z     = (ushort*)alloc((size_t)NPAD * HIDF * 2);  // bf16 z buffer
  ushort* Hhi   = (ushort*)alloc((size_t)NPAD * HIDF * 2);  // bf16 h hi plane
  ushort* Hlo   = (ushort*)alloc((size_t)NPAD * HIDF * 2);  // bf16 h lo plane

  const int nbNode4 = (NN + 3) / 4;      // 12500
  const int nbAggQ = nbNode4 * 4;        // 50000 (node-group x quarter)
  const int nbGemm = (NN + 127) / 128;   // 391
  const int nbBinA = (EE + 4095) / 4096; // 196
  const int nbEdge = (EE + 255) / 256;   // 3125
  const int nbN = (NN + 255) / 256;      // 196

  // prep (W2 frags + wel/wer + bcnt=0 + zero accumulators) + layer-1 node transform
  k_prep<<<17 + nbNode4, 256, 0, stream>>>(x, W1, al1, ar1, W2, al2, ar2,
                                           Z, el1, er1, Bfrag, wel, wer, bcnt,
                                           el2, er2, out3);

  // CSR build
  k_binA<<<nbBinA, 256, 0, stream>>>(src, dst, bcnt, bcoo);
  k_binB<<<BKTN, 256, 0, stream>>>(bcoo, bcnt, rowp, srcs, dstc);

  // Layer 1: edge weights, then quartered aggregate -> H planes + el2/er2
  k_edgep<<<nbEdge, 256, 0, stream>>>(srcs, dstc, el1, er1, e2);
  k_aggq<1><<<nbAggQ, 256, 0, stream>>>(rowp, e2, Z, b1, Hhi, Hlo, wel, wer,
                                        el2, er2, nullptr);

  // Layer 2: GEMM, edge weights, quartered aggregate -> out3, final head
  k_gemm_mfma<<<nbGemm, 256, 0, stream>>>(Hhi, Hlo, Bfrag, Z);
  k_edgep<<<nbEdge, 256, 0, stream>>>(srcs, dstc, el2, er2, e2);
  k_aggq<2><<<nbAggQ, 256, 0, stream>>>(rowp, e2, Z, b2, nullptr, nullptr, Wlin, nullptr,
                                        nullptr, nullptr, out3);
  k_final<<<nbN, 256, 0, stream>>>(out3, blin, out);
}

// Round 9
// 146.526 us; speedup vs baseline: 2.1804x; 2.1804x over previous
//
#include <hip/hip_runtime.h>
#include <math.h>

#define NN 50000
#define EE 800000
#define HIDF 128
#define NPAD 50176   // padded rows for tile overrun (391*128 = 50048)

#define BSHIFT 9
#define BKTN 98      // ceil(50000 / 512)
#define BCAP 10000   // max edges per bucket (mean 8163 -> huge margin)

typedef unsigned int uint;
typedef unsigned short ushort;
typedef unsigned char uchar;
typedef short bf16x8 __attribute__((ext_vector_type(8)));
typedef float f32x4 __attribute__((ext_vector_type(4)));
typedef float f32x2 __attribute__((ext_vector_type(2)));

__device__ inline ushort bf16_rtne(float x) {
  uint u = __float_as_uint(x);
  return (ushort)((u + 0x7fffu + ((u >> 16) & 1u)) >> 16);
}
__device__ inline uint pack2_bf16(float a, float b) {
  return (uint)bf16_rtne(a) | ((uint)bf16_rtne(b) << 16);
}
__device__ inline float rdlanef(float p, int jj) {
  return __uint_as_float(__builtin_amdgcn_readlane(__float_as_uint(p), jj));
}
__device__ inline float lo16(uint z) { return __uint_as_float(z << 16); }
__device__ inline float hi16(uint z) { return __uint_as_float(z & 0xffff0000u); }

// ===================== Prep: W2 frags + wel/wer + bcnt zero + layer-1 node transform =====
__global__ void k_prep(const float* __restrict__ x, const float* __restrict__ W1,
                       const float* __restrict__ al1, const float* __restrict__ ar1,
                       const float* __restrict__ W2, const float* __restrict__ al2,
                       const float* __restrict__ ar2,
                       ushort* __restrict__ z, float* __restrict__ el, float* __restrict__ er,
                       ushort* __restrict__ Bfrag, float* __restrict__ wel,
                       float* __restrict__ wer, int* __restrict__ bcnt) {
  int b = blockIdx.x, tid = threadIdx.x;
  if (b < 16) {
    int e = b * 1024 + tid * 4;
#pragma unroll
    for (int q = 0; q < 4; ++q, ++e) {
      int k = e >> 7, n = e & 127;
      float v = W2[e];
      ushort hi = bf16_rtne(v);
      ushort lo = bf16_rtne(v - __uint_as_float((uint)hi << 16));
      int g = n >> 4, t = k >> 5;
      int l = (n & 15) | (((k >> 3) & 3) << 4);
      int j = k & 7;
      int idx = ((g * 4 + t) * 64 + l) * 8 + j;
      Bfrag[idx] = hi;
      Bfrag[16384 + idx] = lo;
    }
  } else if (b == 16) {
    if (tid < BKTN) bcnt[tid] = 0;
    if (tid < 128) {
      float acc = 0.f;
      for (int k = 0; k < 128; ++k) acc += W2[k * 128 + tid] * al2[k];
      wel[tid] = acc;
    } else {
      int n = tid - 128;
      float acc = 0.f;
      for (int k = 0; k < 128; ++k) acc += W2[k * 128 + n] * ar2[k];
      wer[n] = acc;
    }
  } else {
    int v = (b - 17) * 4 + (tid >> 6);
    if (v >= NN) return;
    int lane = tid & 63;
    float x0 = x[v * 2 + 0];
    float x1 = x[v * 2 + 1];
    int f0 = lane * 2, f1 = f0 + 1;
    float z0 = fmaf(x0, W1[f0], x1 * W1[HIDF + f0]);
    float z1v = fmaf(x0, W1[f1], x1 * W1[HIDF + f1]);
    ((uint*)(z + (size_t)v * HIDF))[lane] = pack2_bf16(z0, z1v);
    float elp = z0 * al1[f0] + z1v * al1[f1];
    float erp = z0 * ar1[f0] + z1v * ar1[f1];
    for (int o = 32; o; o >>= 1) {
      elp += __shfl_xor(elp, o);
      erp += __shfl_xor(erp, o);
    }
    if (lane == 0) { el[v] = elp; er[v] = erp; }
  }
}

// ===================== CSR build: LDS-staged two-level binning =====================
__global__ __launch_bounds__(256) void k_binA(const int* __restrict__ src,
                                              const int* __restrict__ dst,
                                              int* __restrict__ bcnt, uint* __restrict__ bcoo) {
  __shared__ uint stage[4096];
  __shared__ uchar stageb[4096];
  __shared__ int bh[BKTN], bbase[BKTN], gbase[BKTN], lcur[BKTN];
  __shared__ int sc[128];
  int tid = threadIdx.x;
  int e0 = blockIdx.x * 4096;
  int nE = min(4096, EE - e0);
  if (tid < BKTN) bh[tid] = 0;
  __syncthreads();

  int myb[16];
  uint myv[16];
#pragma unroll
  for (int k = 0; k < 16; ++k) {
    int i = e0 + k * 256 + tid;
    myb[k] = -1;
    if (i < EE) {
      int s = src[i], d = dst[i];
      myb[k] = d >> BSHIFT;
      myv[k] = ((uint)s << BSHIFT) | (uint)(d & 511);
      atomicAdd(&bh[myb[k]], 1);
    }
  }
  __syncthreads();

  {
    int v = (tid < BKTN) ? bh[tid] : 0;
    if (tid < 128) sc[tid] = v;
    __syncthreads();
    for (int o = 1; o < 128; o <<= 1) {
      int add = (tid >= o && tid < 128) ? sc[tid - o] : 0;
      __syncthreads();
      if (tid < 128) sc[tid] += add;
      __syncthreads();
    }
    if (tid < BKTN) {
      int excl = sc[tid] - bh[tid];
      bbase[tid] = excl;
      lcur[tid] = excl;
      gbase[tid] = atomicAdd(&bcnt[tid], bh[tid]);
    }
  }
  __syncthreads();

#pragma unroll
  for (int k = 0; k < 16; ++k) {
    if (myb[k] >= 0) {
      int slot = atomicAdd(&lcur[myb[k]], 1);
      stage[slot] = myv[k];
      stageb[slot] = (uchar)myb[k];
    }
  }
  __syncthreads();

  for (int s2 = tid; s2 < nE; s2 += 256) {
    int b = stageb[s2];
    bcoo[(size_t)b * BCAP + gbase[b] + (s2 - bbase[b])] = stage[s2];
  }
}

// Pass B: per-bucket counting sort; integrates the 98-wide bucket scan.
__global__ __launch_bounds__(256) void k_binB(const uint* __restrict__ bcoo,
                                              const int* __restrict__ bcnt,
                                              int* __restrict__ rowp, int* __restrict__ srcs) {
  __shared__ int h[512], pref[512], ps[256];
  __shared__ int basebuf;
  int b = blockIdx.x, tid = threadIdx.x;
  int cnt = bcnt[b];

  {
    int v = (tid < BKTN) ? bcnt[tid] : 0;
    if (tid < 128) ps[tid] = v;
    __syncthreads();
    for (int o = 1; o < 128; o <<= 1) {
      int add = (tid >= o && tid < 128) ? ps[tid - o] : 0;
      __syncthreads();
      if (tid < 128) ps[tid] += add;
      __syncthreads();
    }
    if (tid == 0) {
      basebuf = (b == 0) ? 0 : ps[b - 1];
      if (b == 0) rowp[NN] = EE;
    }
  }
  h[tid] = 0;
  h[tid + 256] = 0;
  __syncthreads();
  int base = basebuf;
  const uint* mc = bcoo + (size_t)b * BCAP;
  for (int i = tid; i < cnt; i += 256) atomicAdd(&h[mc[i] & 511], 1);
  __syncthreads();
  int a0 = h[2 * tid], a1 = h[2 * tid + 1];
  int s = a0 + a1;
  ps[tid] = s;
  __syncthreads();
  for (int o = 1; o < 256; o <<= 1) {
    int add = (tid >= o) ? ps[tid - o] : 0;
    __syncthreads();
    ps[tid] += add;
    __syncthreads();
  }
  int excl = ps[tid] - s;
  pref[2 * tid] = excl;
  pref[2 * tid + 1] = excl + a0;
  __syncthreads();
  int n0 = b << BSHIFT;
  for (int j = tid; j < 512; j += 256)
    if (n0 + j < NN) rowp[n0 + j] = base + pref[j];
  __syncthreads();
  for (int i = tid; i < cnt; i += 256) {
    uint v = mc[i];
    int pos = atomicAdd(&pref[v & 511], 1);
    srcs[base + pos] = (int)(v >> BSHIFT);
  }
}

// ===================== Layer 2 GEMM via MFMA bf16x2-split =====================
__global__ __launch_bounds__(256) void k_gemm_mfma(
    const ushort* __restrict__ Hhi, const ushort* __restrict__ Hlo,
    const ushort* __restrict__ Bfrag, ushort* __restrict__ z) {
  int tid = threadIdx.x;
  int lane = tid & 63;
  int wid = tid >> 6;
  int base = blockIdx.x * 128;

  bf16x8 bhi[2][4], blo[2][4];
  const bf16x8* bp = (const bf16x8*)Bfrag;
#pragma unroll
  for (int gi = 0; gi < 2; ++gi)
#pragma unroll
    for (int t = 0; t < 4; ++t) {
      int idx = ((wid * 2 + gi) * 4 + t) * 64 + lane;
      bhi[gi][t] = bp[idx];
      blo[gi][t] = bp[2048 + idx];
    }

  int arow = lane & 15;
  int koff = (lane >> 4) * 8;
  const bf16x8* ahp = (const bf16x8*)(Hhi + (size_t)(base + arow) * HIDF + koff);
  const bf16x8* alp = (const bf16x8*)(Hlo + (size_t)(base + arow) * HIDF + koff);

  bf16x8 ah[4], av[4];
#pragma unroll
  for (int t = 0; t < 4; ++t) { ah[t] = ahp[t * 4]; av[t] = alp[t * 4]; }

#pragma unroll
  for (int mt = 0; mt < 8; ++mt) {
    bf16x8 nah[4], nav[4];
#pragma unroll
    for (int t = 0; t < 4; ++t) { nah[t] = ah[t]; nav[t] = av[t]; }
    if (mt < 7) {
#pragma unroll
      for (int t = 0; t < 4; ++t) {
        nah[t] = ahp[(mt + 1) * 256 + t * 4];
        nav[t] = alp[(mt + 1) * 256 + t * 4];
      }
    }
    f32x4 c0a = {0.f, 0.f, 0.f, 0.f}, c0b = {0.f, 0.f, 0.f, 0.f};
    f32x4 c1a = {0.f, 0.f, 0.f, 0.f}, c1b = {0.f, 0.f, 0.f, 0.f};
#pragma unroll
    for (int t = 0; t < 4; ++t) {
      f32x4& c0 = (t & 1) ? c0b : c0a;
      f32x4& c1 = (t & 1) ? c1b : c1a;
      c0 = __builtin_amdgcn_mfma_f32_16x16x32_bf16(ah[t], bhi[0][t], c0, 0, 0, 0);
      c1 = __builtin_amdgcn_mfma_f32_16x16x32_bf16(ah[t], bhi[1][t], c1, 0, 0, 0);
      c0 = __builtin_amdgcn_mfma_f32_16x16x32_bf16(ah[t], blo[0][t], c0, 0, 0, 0);
      c1 = __builtin_amdgcn_mfma_f32_16x16x32_bf16(ah[t], blo[1][t], c1, 0, 0, 0);
      c0 = __builtin_amdgcn_mfma_f32_16x16x32_bf16(av[t], bhi[0][t], c0, 0, 0, 0);
      c1 = __builtin_amdgcn_mfma_f32_16x16x32_bf16(av[t], bhi[1][t], c1, 0, 0, 0);
    }
    f32x4 c0 = c0a + c0b;
    f32x4 c1 = c1a + c1b;
    int r0 = base + mt * 16 + (lane >> 4) * 4;
    int cc = wid * 32 + (lane & 15);
    ushort* zp = z + (size_t)r0 * HIDF + cc;
#pragma unroll
    for (int i = 0; i < 4; ++i) {
      zp[i * HIDF] = bf16_rtne(c0[i]);
      zp[i * HIDF + 16] = bf16_rtne(c1[i]);
    }
#pragma unroll
    for (int t = 0; t < 4; ++t) { ah[t] = nah[t]; av[t] = nav[t]; }
  }
}

// ===================== Edge softmax + aggregate (one wave per dst node) =====================
// Full-wave gather: one edge's 256B bf16 row read by 64 lanes (uint each), exact
// pair-granular edge processing. f32x2 accumulator written as vector FMA so the
// compiler can emit v_pk_fma_f32 (2 FMAs/inst); per-lane base pointer hoisted.
#define PAIR(JJ)                                                        \
  {                                                                     \
    float pA = rdlanef(p, (JJ)), pB = rdlanef(p, (JJ) + 1);             \
    int sA = __builtin_amdgcn_readlane(s, (JJ));                        \
    int sB = __builtin_amdgcn_readlane(s, (JJ) + 1);                    \
    uint zA = zl[(uint)sA * 64u];                                       \
    uint zB = zl[(uint)sB * 64u];                                       \
    f32x2 vA = {lo16(zA), hi16(zA)};                                    \
    f32x2 vB = {lo16(zB), hi16(zB)};                                    \
    acc = vA * (f32x2){pA, pA} + acc;                                   \
    acc = vB * (f32x2){pB, pB} + acc;                                   \
  }

template <int MODE>
__global__ void k_aggregate(const int* __restrict__ rowp, const int* __restrict__ srcs,
                            const float* __restrict__ el, const float* __restrict__ er,
                            const ushort* __restrict__ z, const float* __restrict__ bias,
                            ushort* __restrict__ Hhi, ushort* __restrict__ Hlo,
                            const float* __restrict__ wel, const float* __restrict__ wer,
                            float* __restrict__ elo, float* __restrict__ ero,
                            float* __restrict__ out,
                            const float* __restrict__ Wlin, const float* __restrict__ blin) {
  int v = blockIdx.x * 4 + (threadIdx.x >> 6);
  if (v >= NN) return;
  int lane = threadIdx.x & 63;
  int beg = rowp[v], end = rowp[v + 1];
  float erv = er[v];
  float psum = 0.f;
  f32x2 acc = {0.f, 0.f};
  const uint* zl = (const uint*)z + lane;

  for (int cb = beg; cb < end; cb += 64) {
    int j = cb + lane;
    int s = srcs[min(j, end - 1)];
    float t = el[s] + erv;
    t = fmaxf(t, 0.2f * t);                 // leaky_relu(t, 0.2)
    float p = (j < end) ? __expf(t) : 0.f;
    psum += p;
    int cnt = min(64, end - cb);
    int bb = 0;
    for (; bb + 16 <= cnt; bb += 16) {
#pragma unroll
      for (int u = 0; u < 16; u += 2) PAIR(bb + u)
    }
    for (; bb < cnt; bb += 2) PAIR(bb)      // pair tail; odd edge padded by p=0 lane
  }

  float denom = psum;
  for (int o = 32; o; o >>= 1) denom += __shfl_xor(denom, o);
  float inv = 1.0f / (denom + 1e-9f);
  float2 bv = ((const float2*)bias)[lane];
  float ox = fmaxf(fmaf(acc.x, inv, bv.x), 0.f);
  float oy = fmaxf(fmaf(acc.y, inv, bv.y), 0.f);

  if (MODE == 1) {
    ushort hx = bf16_rtne(ox), hy = bf16_rtne(oy);
    ((uint*)Hhi)[(size_t)v * 64 + lane] = (uint)hx | ((uint)hy << 16);
    float lx = ox - __uint_as_float((uint)hx << 16);
    float ly = oy - __uint_as_float((uint)hy << 16);
    ((uint*)Hlo)[(size_t)v * 64 + lane] = pack2_bf16(lx, ly);
    float2 wl = ((const float2*)wel)[lane];
    float2 wr = ((const float2*)wer)[lane];
    float ep = ox * wl.x + oy * wl.y;
    float rp = ox * wr.x + oy * wr.y;
    for (int o = 32; o; o >>= 1) {
      ep += __shfl_xor(ep, o);
      rp += __shfl_xor(rp, o);
    }
    if (lane == 0) { elo[v] = ep; ero[v] = rp; }
  } else {
    int f0 = lane * 2;
    const float* w0 = &Wlin[f0 * 3];
    float d0 = fmaf(ox, w0[0], oy * w0[3]);
    float d1 = fmaf(ox, w0[1], oy * w0[4]);
    float d2 = fmaf(ox, w0[2], oy * w0[5]);
    for (int o = 32; o; o >>= 1) {
      d0 += __shfl_xor(d0, o);
      d1 += __shfl_xor(d1, o);
      d2 += __shfl_xor(d2, o);
    }
    if (lane == 0) {
      float s0 = 1.f / (1.f + __expf(-(d0 + blin[0])));
      float s1 = 1.f / (1.f + __expf(-(d1 + blin[1])));
      float s2 = 1.f / (1.f + __expf(-(d2 + blin[2])));
      out[v] = (s0 + s1 + s2) * (1.f / 3.f);
    }
  }
}

// ===================== host =====================
extern "C" void kernel_launch(void* const* d_in, const int* in_sizes, int n_in,
                              void* d_out, int out_size, void* d_ws, size_t ws_size,
                              hipStream_t stream) {
  const float* x    = (const float*)d_in[0];
  const int*   src  = (const int*)d_in[1];
  const int*   dst  = (const int*)d_in[2];
  const float* W1   = (const float*)d_in[3];
  const float* al1  = (const float*)d_in[4];
  const float* ar1  = (const float*)d_in[5];
  const float* b1   = (const float*)d_in[6];
  const float* W2   = (const float*)d_in[7];
  const float* al2  = (const float*)d_in[8];
  const float* ar2  = (const float*)d_in[9];
  const float* b2   = (const float*)d_in[10];
  const float* Wlin = (const float*)d_in[11];
  const float* blin = (const float*)d_in[12];
  float* out = (float*)d_out;

  char* ws = (char*)d_ws;
  size_t off = 0;
  auto alloc = [&](size_t bytes) -> char* {
    char* p = ws + off;
    off += (bytes + 255) & ~(size_t)255;
    return p;
  };
  int*    rowp    = (int*)alloc((size_t)(NN + 1) * 4);
  int*    srcs    = (int*)alloc((size_t)EE * 4);
  int*    bcnt    = (int*)alloc(BKTN * 4);
  uint*   bcoo    = (uint*)alloc((size_t)BKTN * BCAP * 4);
  float*  el1     = (float*)alloc((size_t)NN * 4);
  float*  er1     = (float*)alloc((size_t)NN * 4);
  float*  el2     = (float*)alloc((size_t)NN * 4);
  float*  er2     = (float*)alloc((size_t)NN * 4);
  float*  wel     = (float*)alloc(HIDF * 4);
  float*  wer     = (float*)alloc(HIDF * 4);
  ushort* Bfrag   = (ushort*)alloc(2 * 16384 * 2);            // hi+lo frag planes
  ushort* Z       = (ushort*)alloc((size_t)NPAD * HIDF * 2);  // bf16 z buffer
  ushort* Hhi     = (ushort*)alloc((size_t)NPAD * HIDF * 2);  // bf16 h hi plane
  ushort* Hlo     = (ushort*)alloc((size_t)NPAD * HIDF * 2);  // bf16 h lo plane

  const int nbNode4 = (NN + 3) / 4;      // 12500
  const int nbGemm = (NN + 127) / 128;   // 391
  const int nbBinA = (EE + 4095) / 4096; // 196

  // prep (W2 frags + wel/wer + bcnt=0) and layer-1 node transform, single launch
  k_prep<<<17 + nbNode4, 256, 0, stream>>>(x, W1, al1, ar1, W2, al2, ar2,
                                           Z, el1, er1, Bfrag, wel, wer, bcnt);

  // CSR build (two-level binning; scan folded into binB)
  k_binA<<<nbBinA, 256, 0, stream>>>(src, dst, bcnt, bcoo);
  k_binB<<<BKTN, 256, 0, stream>>>(bcoo, bcnt, rowp, srcs);

  // Layer 1 aggregate -> h (bf16 hi/lo) + el2/er2
  k_aggregate<1><<<nbNode4, 256, 0, stream>>>(rowp, srcs, el1, er1, Z, b1,
                                              Hhi, Hlo, wel, wer, el2, er2,
                                              nullptr, nullptr, nullptr);

  // Layer 2
  k_gemm_mfma<<<nbGemm, 256, 0, stream>>>(Hhi, Hlo, Bfrag, Z);
  k_aggregate<2><<<nbNode4, 256, 0, stream>>>(rowp, srcs, el2, er2, Z, b2,
                                              nullptr, nullptr, nullptr, nullptr, nullptr, nullptr,
                                              out, Wlin, blin);
}

// Round 10
// 120.475 us; speedup vs baseline: 2.6519x; 1.2162x over previous
//
#include <hip/hip_runtime.h>
#include <math.h>

#define NN 50000
#define EE 800000
#define HIDF 128
#define NPAD 50176   // padded rows for tile overrun (391*128 = 50048)

#define BSHIFT 9
#define BKTN 98      // ceil(50000 / 512)
#define BCAP 10000   // max edges per bucket (mean 8163 -> huge margin)

typedef unsigned int uint;
typedef unsigned short ushort;
typedef unsigned char uchar;
typedef short bf16x8 __attribute__((ext_vector_type(8)));
typedef float f32x4 __attribute__((ext_vector_type(4)));
typedef float f32x2 __attribute__((ext_vector_type(2)));

__device__ inline ushort bf16_rtne(float x) {
  uint u = __float_as_uint(x);
  return (ushort)((u + 0x7fffu + ((u >> 16) & 1u)) >> 16);
}
__device__ inline uint pack2_bf16(float a, float b) {
  return (uint)bf16_rtne(a) | ((uint)bf16_rtne(b) << 16);
}
__device__ inline float rdlanef(float p, int jj) {
  return __uint_as_float(__builtin_amdgcn_readlane(__float_as_uint(p), jj));
}
__device__ inline float lo16(uint z) { return __uint_as_float(z << 16); }
__device__ inline float hi16(uint z) { return __uint_as_float(z & 0xffff0000u); }

// ===================== Prep: W2 frags + wel/wer + W1-projections + bcnt zero =====
// blocks 0..15: W2 -> bf16 hi/lo B-fragments in MFMA lane order
// block 16:     wel = W2@al2, wer = W2@ar2, params = {W1@al1, W1@ar1} (rank-2), bcnt = 0
__global__ void k_prep(const float* __restrict__ W1, const float* __restrict__ al1,
                       const float* __restrict__ ar1,
                       const float* __restrict__ W2, const float* __restrict__ al2,
                       const float* __restrict__ ar2,
                       ushort* __restrict__ Bfrag, float* __restrict__ wel,
                       float* __restrict__ wer, float* __restrict__ params,
                       int* __restrict__ bcnt) {
  int b = blockIdx.x, tid = threadIdx.x;
  if (b < 16) {
    int e = b * 1024 + tid * 4;
#pragma unroll
    for (int q = 0; q < 4; ++q, ++e) {
      int k = e >> 7, n = e & 127;
      float v = W2[e];
      ushort hi = bf16_rtne(v);
      ushort lo = bf16_rtne(v - __uint_as_float((uint)hi << 16));
      int g = n >> 4, t = k >> 5;
      int l = (n & 15) | (((k >> 3) & 3) << 4);
      int j = k & 7;
      int idx = ((g * 4 + t) * 64 + l) * 8 + j;
      Bfrag[idx] = hi;
      Bfrag[16384 + idx] = lo;
    }
  } else {
    if (tid < BKTN) bcnt[tid] = 0;
    if (tid < 128) {
      float acc = 0.f;
      for (int k = 0; k < 128; ++k) acc += W2[k * 128 + tid] * al2[k];
      wel[tid] = acc;
    } else {
      int n = tid - 128;
      float acc = 0.f;
      for (int k = 0; k < 128; ++k) acc += W2[k * 128 + n] * ar2[k];
      wer[n] = acc;
    }
    if (tid < 4) {
      // params = {wl1x, wl1y, wr1x, wr1y}: wl1r = sum_f W1[r][f]*al1[f], etc.
      const float* vec = (tid & 2) ? ar1 : al1;
      const float* wrow = W1 + (tid & 1) * HIDF;
      float acc = 0.f;
      for (int f = 0; f < HIDF; ++f) acc += wrow[f] * vec[f];
      params[tid] = acc;
    }
  }
}

// ===================== CSR build: LDS-staged two-level binning =====================
__global__ __launch_bounds__(256) void k_binA(const int* __restrict__ src,
                                              const int* __restrict__ dst,
                                              int* __restrict__ bcnt, uint* __restrict__ bcoo) {
  __shared__ uint stage[4096];
  __shared__ uchar stageb[4096];
  __shared__ int bh[BKTN], bbase[BKTN], gbase[BKTN], lcur[BKTN];
  __shared__ int sc[128];
  int tid = threadIdx.x;
  int e0 = blockIdx.x * 4096;
  int nE = min(4096, EE - e0);
  if (tid < BKTN) bh[tid] = 0;
  __syncthreads();

  int myb[16];
  uint myv[16];
#pragma unroll
  for (int k = 0; k < 16; ++k) {
    int i = e0 + k * 256 + tid;
    myb[k] = -1;
    if (i < EE) {
      int s = src[i], d = dst[i];
      myb[k] = d >> BSHIFT;
      myv[k] = ((uint)s << BSHIFT) | (uint)(d & 511);
      atomicAdd(&bh[myb[k]], 1);
    }
  }
  __syncthreads();

  {
    int v = (tid < BKTN) ? bh[tid] : 0;
    if (tid < 128) sc[tid] = v;
    __syncthreads();
    for (int o = 1; o < 128; o <<= 1) {
      int add = (tid >= o && tid < 128) ? sc[tid - o] : 0;
      __syncthreads();
      if (tid < 128) sc[tid] += add;
      __syncthreads();
    }
    if (tid < BKTN) {
      int excl = sc[tid] - bh[tid];
      bbase[tid] = excl;
      lcur[tid] = excl;
      gbase[tid] = atomicAdd(&bcnt[tid], bh[tid]);
    }
  }
  __syncthreads();

#pragma unroll
  for (int k = 0; k < 16; ++k) {
    if (myb[k] >= 0) {
      int slot = atomicAdd(&lcur[myb[k]], 1);
      stage[slot] = myv[k];
      stageb[slot] = (uchar)myb[k];
    }
  }
  __syncthreads();

  for (int s2 = tid; s2 < nE; s2 += 256) {
    int b = stageb[s2];
    bcoo[(size_t)b * BCAP + gbase[b] + (s2 - bbase[b])] = stage[s2];
  }
}

// Pass B: per-bucket counting sort; integrates the 98-wide bucket scan.
__global__ __launch_bounds__(256) void k_binB(const uint* __restrict__ bcoo,
                                              const int* __restrict__ bcnt,
                                              int* __restrict__ rowp, int* __restrict__ srcs) {
  __shared__ int h[512], pref[512], ps[256];
  __shared__ int basebuf;
  int b = blockIdx.x, tid = threadIdx.x;
  int cnt = bcnt[b];

  {
    int v = (tid < BKTN) ? bcnt[tid] : 0;
    if (tid < 128) ps[tid] = v;
    __syncthreads();
    for (int o = 1; o < 128; o <<= 1) {
      int add = (tid >= o && tid < 128) ? ps[tid - o] : 0;
      __syncthreads();
      if (tid < 128) ps[tid] += add;
      __syncthreads();
    }
    if (tid == 0) {
      basebuf = (b == 0) ? 0 : ps[b - 1];
      if (b == 0) rowp[NN] = EE;
    }
  }
  h[tid] = 0;
  h[tid + 256] = 0;
  __syncthreads();
  int base = basebuf;
  const uint* mc = bcoo + (size_t)b * BCAP;
  for (int i = tid; i < cnt; i += 256) atomicAdd(&h[mc[i] & 511], 1);
  __syncthreads();
  int a0 = h[2 * tid], a1 = h[2 * tid + 1];
  int s = a0 + a1;
  ps[tid] = s;
  __syncthreads();
  for (int o = 1; o < 256; o <<= 1) {
    int add = (tid >= o) ? ps[tid - o] : 0;
    __syncthreads();
    ps[tid] += add;
    __syncthreads();
  }
  int excl = ps[tid] - s;
  pref[2 * tid] = excl;
  pref[2 * tid + 1] = excl + a0;
  __syncthreads();
  int n0 = b << BSHIFT;
  for (int j = tid; j < 512; j += 256)
    if (n0 + j < NN) rowp[n0 + j] = base + pref[j];
  __syncthreads();
  for (int i = tid; i < cnt; i += 256) {
    uint v = mc[i];
    int pos = atomicAdd(&pref[v & 511], 1);
    srcs[base + pos] = (int)(v >> BSHIFT);
  }
}

// ===================== Layer-1 aggregate via rank-2 identity =====================
// sum_j a_j z1[s_j] = (sum_j a_j x[s_j]) @ W1 ; el1[s] = x[s].wl1 (2-term dot).
// Per edge: ONE float2 gather from L2-resident x (400KB); lane-parallel, no readlanes.
// Epilogue: h = relu(agg@W1 + b1) -> Hhi/Hlo bf16 planes + el2/er2 via wel/wer.
__global__ void k_agg1(const int* __restrict__ rowp, const int* __restrict__ srcs,
                       const float* __restrict__ x, const float* __restrict__ params,
                       const float* __restrict__ W1, const float* __restrict__ b1,
                       ushort* __restrict__ Hhi, ushort* __restrict__ Hlo,
                       const float* __restrict__ wel, const float* __restrict__ wer,
                       float* __restrict__ el2, float* __restrict__ er2) {
  int v = blockIdx.x * 4 + (threadIdx.x >> 6);
  if (v >= NN) return;
  int lane = threadIdx.x & 63;
  float wl1x = params[0], wl1y = params[1], wr1x = params[2], wr1y = params[3];
  float2 xv = ((const float2*)x)[v];
  float erv = fmaf(xv.x, wr1x, xv.y * wr1y);
  int beg = rowp[v], end = rowp[v + 1];

  float psum = 0.f, ax = 0.f, ay = 0.f;
  for (int j = beg + lane; j < end; j += 64) {
    int s = srcs[j];
    float2 xs = ((const float2*)x)[s];
    float t = fmaf(xs.x, wl1x, xs.y * wl1y) + erv;
    t = fmaxf(t, 0.2f * t);                 // leaky_relu(t, 0.2)
    float p = __expf(t);
    psum += p;
    ax = fmaf(p, xs.x, ax);
    ay = fmaf(p, xs.y, ay);
  }
  for (int o = 32; o; o >>= 1) {
    psum += __shfl_xor(psum, o);
    ax += __shfl_xor(ax, o);
    ay += __shfl_xor(ay, o);
  }
  float inv = 1.0f / (psum + 1e-9f);
  ax *= inv;
  ay *= inv;

  // h features: lane owns cols f0=2*lane, f0+1 of the 2x128 matvec
  float2 w0 = ((const float2*)W1)[lane];          // W1[0][f0], W1[0][f1]
  float2 w1 = ((const float2*)(W1 + HIDF))[lane]; // W1[1][f0], W1[1][f1]
  float2 bv = ((const float2*)b1)[lane];
  float ox = fmaxf(fmaf(ax, w0.x, fmaf(ay, w1.x, bv.x)), 0.f);
  float oy = fmaxf(fmaf(ax, w0.y, fmaf(ay, w1.y, bv.y)), 0.f);

  ushort hx = bf16_rtne(ox), hy = bf16_rtne(oy);
  ((uint*)Hhi)[(size_t)v * 64 + lane] = (uint)hx | ((uint)hy << 16);
  float lx = ox - __uint_as_float((uint)hx << 16);
  float ly = oy - __uint_as_float((uint)hy << 16);
  ((uint*)Hlo)[(size_t)v * 64 + lane] = pack2_bf16(lx, ly);
  float2 wl = ((const float2*)wel)[lane];
  float2 wr = ((const float2*)wer)[lane];
  float ep = ox * wl.x + oy * wl.y;
  float rp = ox * wr.x + oy * wr.y;
  for (int o = 32; o; o >>= 1) {
    ep += __shfl_xor(ep, o);
    rp += __shfl_xor(rp, o);
  }
  if (lane == 0) { el2[v] = ep; er2[v] = rp; }
}

// ===================== Layer 2 GEMM via MFMA bf16x2-split =====================
__global__ __launch_bounds__(256) void k_gemm_mfma(
    const ushort* __restrict__ Hhi, const ushort* __restrict__ Hlo,
    const ushort* __restrict__ Bfrag, ushort* __restrict__ z) {
  int tid = threadIdx.x;
  int lane = tid & 63;
  int wid = tid >> 6;
  int base = blockIdx.x * 128;

  bf16x8 bhi[2][4], blo[2][4];
  const bf16x8* bp = (const bf16x8*)Bfrag;
#pragma unroll
  for (int gi = 0; gi < 2; ++gi)
#pragma unroll
    for (int t = 0; t < 4; ++t) {
      int idx = ((wid * 2 + gi) * 4 + t) * 64 + lane;
      bhi[gi][t] = bp[idx];
      blo[gi][t] = bp[2048 + idx];
    }

  int arow = lane & 15;
  int koff = (lane >> 4) * 8;
  const bf16x8* ahp = (const bf16x8*)(Hhi + (size_t)(base + arow) * HIDF + koff);
  const bf16x8* alp = (const bf16x8*)(Hlo + (size_t)(base + arow) * HIDF + koff);

  bf16x8 ah[4], av[4];
#pragma unroll
  for (int t = 0; t < 4; ++t) { ah[t] = ahp[t * 4]; av[t] = alp[t * 4]; }

#pragma unroll
  for (int mt = 0; mt < 8; ++mt) {
    bf16x8 nah[4], nav[4];
#pragma unroll
    for (int t = 0; t < 4; ++t) { nah[t] = ah[t]; nav[t] = av[t]; }
    if (mt < 7) {
#pragma unroll
      for (int t = 0; t < 4; ++t) {
        nah[t] = ahp[(mt + 1) * 256 + t * 4];
        nav[t] = alp[(mt + 1) * 256 + t * 4];
      }
    }
    f32x4 c0a = {0.f, 0.f, 0.f, 0.f}, c0b = {0.f, 0.f, 0.f, 0.f};
    f32x4 c1a = {0.f, 0.f, 0.f, 0.f}, c1b = {0.f, 0.f, 0.f, 0.f};
#pragma unroll
    for (int t = 0; t < 4; ++t) {
      f32x4& c0 = (t & 1) ? c0b : c0a;
      f32x4& c1 = (t & 1) ? c1b : c1a;
      c0 = __builtin_amdgcn_mfma_f32_16x16x32_bf16(ah[t], bhi[0][t], c0, 0, 0, 0);
      c1 = __builtin_amdgcn_mfma_f32_16x16x32_bf16(ah[t], bhi[1][t], c1, 0, 0, 0);
      c0 = __builtin_amdgcn_mfma_f32_16x16x32_bf16(ah[t], blo[0][t], c0, 0, 0, 0);
      c1 = __builtin_amdgcn_mfma_f32_16x16x32_bf16(ah[t], blo[1][t], c1, 0, 0, 0);
      c0 = __builtin_amdgcn_mfma_f32_16x16x32_bf16(av[t], bhi[0][t], c0, 0, 0, 0);
      c1 = __builtin_amdgcn_mfma_f32_16x16x32_bf16(av[t], bhi[1][t], c1, 0, 0, 0);
    }
    f32x4 c0 = c0a + c0b;
    f32x4 c1 = c1a + c1b;
    int r0 = base + mt * 16 + (lane >> 4) * 4;
    int cc = wid * 32 + (lane & 15);
    ushort* zp = z + (size_t)r0 * HIDF + cc;
#pragma unroll
    for (int i = 0; i < 4; ++i) {
      zp[i * HIDF] = bf16_rtne(c0[i]);
      zp[i * HIDF + 16] = bf16_rtne(c1[i]);
    }
#pragma unroll
    for (int t = 0; t < 4; ++t) { ah[t] = nah[t]; av[t] = nav[t]; }
  }
}

// ===================== Layer-2 edge softmax + aggregate + fused head =====================
#define PAIR(JJ)                                                        \
  {                                                                     \
    float pA = rdlanef(p, (JJ)), pB = rdlanef(p, (JJ) + 1);             \
    int sA = __builtin_amdgcn_readlane(s, (JJ));                        \
    int sB = __builtin_amdgcn_readlane(s, (JJ) + 1);                    \
    uint zA = zl[(uint)sA * 64u];                                       \
    uint zB = zl[(uint)sB * 64u];                                       \
    f32x2 vA = {lo16(zA), hi16(zA)};                                    \
    f32x2 vB = {lo16(zB), hi16(zB)};                                    \
    acc = vA * (f32x2){pA, pA} + acc;                                   \
    acc = vB * (f32x2){pB, pB} + acc;                                   \
  }

__global__ void k_agg2(const int* __restrict__ rowp, const int* __restrict__ srcs,
                       const float* __restrict__ el, const float* __restrict__ er,
                       const ushort* __restrict__ z, const float* __restrict__ bias,
                       float* __restrict__ out,
                       const float* __restrict__ Wlin, const float* __restrict__ blin) {
  int v = blockIdx.x * 4 + (threadIdx.x >> 6);
  if (v >= NN) return;
  int lane = threadIdx.x & 63;
  int beg = rowp[v], end = rowp[v + 1];
  float erv = er[v];
  float psum = 0.f;
  f32x2 acc = {0.f, 0.f};
  const uint* zl = (const uint*)z + lane;

  for (int cb = beg; cb < end; cb += 64) {
    int j = cb + lane;
    int s = srcs[min(j, end - 1)];
    float t = el[s] + erv;
    t = fmaxf(t, 0.2f * t);                 // leaky_relu(t, 0.2)
    float p = (j < end) ? __expf(t) : 0.f;
    psum += p;
    int cnt = min(64, end - cb);
    int bb = 0;
    for (; bb + 16 <= cnt; bb += 16) {
#pragma unroll
      for (int u = 0; u < 16; u += 2) PAIR(bb + u)
    }
    for (; bb < cnt; bb += 2) PAIR(bb)      // pair tail; odd edge padded by p=0 lane
  }

  float denom = psum;
  for (int o = 32; o; o >>= 1) denom += __shfl_xor(denom, o);
  float inv = 1.0f / (denom + 1e-9f);
  float2 bv = ((const float2*)bias)[lane];
  float ox = fmaxf(fmaf(acc.x, inv, bv.x), 0.f);
  float oy = fmaxf(fmaf(acc.y, inv, bv.y), 0.f);

  int f0 = lane * 2;
  const float* w0 = &Wlin[f0 * 3];
  float d0 = fmaf(ox, w0[0], oy * w0[3]);
  float d1 = fmaf(ox, w0[1], oy * w0[4]);
  float d2 = fmaf(ox, w0[2], oy * w0[5]);
  for (int o = 32; o; o >>= 1) {
    d0 += __shfl_xor(d0, o);
    d1 += __shfl_xor(d1, o);
    d2 += __shfl_xor(d2, o);
  }
  if (lane == 0) {
    float s0 = 1.f / (1.f + __expf(-(d0 + blin[0])));
    float s1 = 1.f / (1.f + __expf(-(d1 + blin[1])));
    float s2 = 1.f / (1.f + __expf(-(d2 + blin[2])));
    out[v] = (s0 + s1 + s2) * (1.f / 3.f);
  }
}

// ===================== host =====================
extern "C" void kernel_launch(void* const* d_in, const int* in_sizes, int n_in,
                              void* d_out, int out_size, void* d_ws, size_t ws_size,
                              hipStream_t stream) {
  const float* x    = (const float*)d_in[0];
  const int*   src  = (const int*)d_in[1];
  const int*   dst  = (const int*)d_in[2];
  const float* W1   = (const float*)d_in[3];
  const float* al1  = (const float*)d_in[4];
  const float* ar1  = (const float*)d_in[5];
  const float* b1   = (const float*)d_in[6];
  const float* W2   = (const float*)d_in[7];
  const float* al2  = (const float*)d_in[8];
  const float* ar2  = (const float*)d_in[9];
  const float* b2   = (const float*)d_in[10];
  const float* Wlin = (const float*)d_in[11];
  const float* blin = (const float*)d_in[12];
  float* out = (float*)d_out;

  char* ws = (char*)d_ws;
  size_t off = 0;
  auto alloc = [&](size_t bytes) -> char* {
    char* p = ws + off;
    off += (bytes + 255) & ~(size_t)255;
    return p;
  };
  int*    rowp   = (int*)alloc((size_t)(NN + 1) * 4);
  int*    srcs   = (int*)alloc((size_t)EE * 4);
  int*    bcnt   = (int*)alloc(BKTN * 4);
  uint*   bcoo   = (uint*)alloc((size_t)BKTN * BCAP * 4);
  float*  el2    = (float*)alloc((size_t)NN * 4);
  float*  er2    = (float*)alloc((size_t)NN * 4);
  float*  wel    = (float*)alloc(HIDF * 4);
  float*  wer    = (float*)alloc(HIDF * 4);
  float*  params = (float*)alloc(16 * 4);
  ushort* Bfrag  = (ushort*)alloc(2 * 16384 * 2);            // hi+lo frag planes
  ushort* Z      = (ushort*)alloc((size_t)NPAD * HIDF * 2);  // bf16 z2 buffer
  ushort* Hhi    = (ushort*)alloc((size_t)NPAD * HIDF * 2);  // bf16 h hi plane
  ushort* Hlo    = (ushort*)alloc((size_t)NPAD * HIDF * 2);  // bf16 h lo plane

  const int nbNode4 = (NN + 3) / 4;      // 12500
  const int nbGemm = (NN + 127) / 128;   // 391
  const int nbBinA = (EE + 4095) / 4096; // 196

  // prep: W2 frags + wel/wer + rank-2 W1 projections + bcnt=0 (17 blocks, tiny)
  k_prep<<<17, 256, 0, stream>>>(W1, al1, ar1, W2, al2, ar2,
                                 Bfrag, wel, wer, params, bcnt);

  // CSR build (two-level binning; scan folded into binB)
  k_binA<<<nbBinA, 256, 0, stream>>>(src, dst, bcnt, bcoo);
  k_binB<<<BKTN, 256, 0, stream>>>(bcoo, bcnt, rowp, srcs);

  // Layer 1: rank-2 aggregate (8B gathers) -> h planes + el2/er2
  k_agg1<<<nbNode4, 256, 0, stream>>>(rowp, srcs, x, params, W1, b1,
                                      Hhi, Hlo, wel, wer, el2, er2);

  // Layer 2: GEMM -> z2, then gather-aggregate + fused head
  k_gemm_mfma<<<nbGemm, 256, 0, stream>>>(Hhi, Hlo, Bfrag, Z);
  k_agg2<<<nbNode4, 256, 0, stream>>>(rowp, srcs, el2, er2, Z, b2, out, Wlin, blin);
}